// Round 20
// baseline (248.127 us; speedup 1.0000x reference)
//
#include <hip/hip_runtime.h>

// bf16 handled as raw ushort (bf16 = top 16 bits of fp32).
typedef unsigned short bfu;
typedef unsigned int u32;
typedef __attribute__((ext_vector_type(8))) short bf16x8;   // 8 bf16 = 4 VGPRs
typedef __attribute__((ext_vector_type(4))) float f32x4;

#define SCALE_F 0.17677669529663687f

__device__ __forceinline__ bfu f2b(float f) {
  unsigned int u = __float_as_uint(f);
  u += 0x7fffu + ((u >> 16) & 1u);   // round-to-nearest-even
  return (bfu)(u >> 16);
}
__device__ __forceinline__ unsigned pk2(float a, float b) {
  return ((unsigned)f2b(b) << 16) | (unsigned)f2b(a);
}
__device__ __forceinline__ void gload_lds16(const void* g, void* l) {
  __builtin_amdgcn_global_load_lds(
      (const __attribute__((address_space(1))) u32*)g,
      (__attribute__((address_space(3))) u32*)l, 16, 0, 0);
}

// r15/r17-verified fragment permutation: dest lane (l15,l4), element e reads
// source lane l15 + 32*(l4&1) (e<4) / +16 (e>=4), register pair s[n = l4>>1].
__device__ __forceinline__ bf16x8 permfrag(uint2 s0, uint2 s1,
                                           int bpA, int bpB, int nsel) {
  u32 a0x = __builtin_amdgcn_ds_bpermute(bpA, (int)s0.x);
  u32 a0y = __builtin_amdgcn_ds_bpermute(bpA, (int)s0.y);
  u32 a1x = __builtin_amdgcn_ds_bpermute(bpA, (int)s1.x);
  u32 a1y = __builtin_amdgcn_ds_bpermute(bpA, (int)s1.y);
  u32 b0x = __builtin_amdgcn_ds_bpermute(bpB, (int)s0.x);
  u32 b0y = __builtin_amdgcn_ds_bpermute(bpB, (int)s0.y);
  u32 b1x = __builtin_amdgcn_ds_bpermute(bpB, (int)s1.x);
  u32 b1y = __builtin_amdgcn_ds_bpermute(bpB, (int)s1.y);
  union { uint4 u; bf16x8 v; } cv;
  cv.u.x = nsel ? a1x : a0x;
  cv.u.y = nsel ? a1y : a0y;
  cv.u.z = nsel ? b1x : b0x;
  cv.u.w = nsel ? b1y : b0y;
  return cv.v;
}

// Prep: cvt w_qkv [768][256] f32 -> bf16 (N x K), w_out [256][256] likewise,
// and gather the 64x64 relative-position bias table (f32).
__global__ void prep_kernel(const float* __restrict__ wq, const float* __restrict__ wo,
                            const float* __restrict__ pe, const int* __restrict__ rel,
                            bfu* __restrict__ wqB, bfu* __restrict__ woB,
                            float* __restrict__ bias)
{
  int t = blockIdx.x * 256 + threadIdx.x;
  if (t < 196608) wqB[t] = f2b(wq[t]);
  if (t < 65536)  woB[t] = f2b(wo[t]);
  if (t < 4096)   { int r0 = rel[2 * t], r1 = rel[2 * t + 1]; bias[t] = pe[r0 * 15 + r1]; }
}

// Fused qkv-projection + window attention at EXACTLY 64 KB LDS so TWO blocks
// co-reside per CU (r17 proved 33.8 KB -> 2 blocks; r15 proved 72.7 KB -> 1).
// One block per (bl, win), 256 thr = 4 waves, 2 heads/wave sequentially.
// Q via ds_bpermute (r15-verified); V register-resident via permfrag
// (r17-verified); K and P in LDS (ps aliases ks); inv via __shfl (no LDS).
// LDS: xwin 32 KB + 4 x 8192 = 65536 B.
__global__ __launch_bounds__(256)
void qkv_attn(const float* __restrict__ x, const bfu* __restrict__ wqB,
              const float* __restrict__ b_qkv, const float* __restrict__ bias,
              bfu* __restrict__ aout)
{
  __shared__ __align__(16) char slds[65536];
  const int t = threadIdx.x;
  const int lane = t & 63, wid = t >> 6;       // 4 waves
  const int l15 = lane & 15, l4 = lane >> 4;
  const int blwin = blockIdx.x;
  const int bl = blwin >> 8, win = blwin & 255;

  // ---- stage x window: wave stages 16 tokens (2 y-rows) as bf16, swizzled ----
  #pragma unroll
  for (int i = 0; i < 16; ++i) {
    int tok = (wid << 4) + i;
    int y = ((win >> 4) << 3) | (tok >> 3);
    int xp = ((win & 15) << 3) | (tok & 7);
    const float* px = x + (((size_t)bl * 16384) + (size_t)y * 128 + xp) * 256 + (lane << 2);
    float4 v = *(const float4*)px;
    uint2 d; d.x = pk2(v.x, v.y); d.y = pk2(v.z, v.w);
    *(uint2*)(slds + tok * 512 + (((lane >> 1) ^ (tok & 15)) << 4) + ((lane & 1) << 3)) = d;
  }
  __syncthreads();   // only block-wide barrier; waves independent afterwards

  char* wbl = slds + 32768 + wid * 8192;
  char* ksB = wbl;                       // 5120 B (K), then overwritten by
  char* psB = wbl;                       // 8192 B (P) after kf is in regs

  const int bpA = (l15 + ((l4 & 1) << 5)) << 2;
  const int bpB = bpA + 64;
  const int nsel = l4 >> 1;

  #pragma unroll 1
  for (int hh = 0; hh < 2; ++hh) {
    const int h = (wid << 1) | hh;

    // ---- fused Q/K/V mini-GEMMs (r12/r15-verified loop) ----
    const bfu* wQ = wqB + (size_t)(h * 32) * 256;
    const bfu* wK = wqB + (size_t)(256 + h * 32) * 256;
    const bfu* wV = wqB + (size_t)(512 + h * 32) * 256;
    const int woff = l15 * 256 + (l4 << 3);
    f32x4 aQ[2][4] = {}, aK[2][4] = {}, aV[4][2] = {};
    #pragma unroll
    for (int kt = 0; kt < 8; ++kt) {
      bf16x8 xf[4];
      #pragma unroll
      for (int m = 0; m < 4; ++m) {
        int tok = (m << 4) + l15;
        int u = ((kt << 2) + l4) ^ (tok & 15);
        xf[m] = *(const bf16x8*)(slds + tok * 512 + (u << 4));
      }
      bf16x8 q0 = *(const bf16x8*)(wQ + woff + (kt << 5));
      bf16x8 q1 = *(const bf16x8*)(wQ + woff + (kt << 5) + 4096);
      bf16x8 k0 = *(const bf16x8*)(wK + woff + (kt << 5));
      bf16x8 k1 = *(const bf16x8*)(wK + woff + (kt << 5) + 4096);
      bf16x8 v0 = *(const bf16x8*)(wV + woff + (kt << 5));
      bf16x8 v1 = *(const bf16x8*)(wV + woff + (kt << 5) + 4096);
      #pragma unroll
      for (int m = 0; m < 4; ++m) {
        aQ[0][m] = __builtin_amdgcn_mfma_f32_16x16x32_bf16(q0, xf[m], aQ[0][m], 0, 0, 0);
        aQ[1][m] = __builtin_amdgcn_mfma_f32_16x16x32_bf16(q1, xf[m], aQ[1][m], 0, 0, 0);
        aK[0][m] = __builtin_amdgcn_mfma_f32_16x16x32_bf16(k0, xf[m], aK[0][m], 0, 0, 0);
        aK[1][m] = __builtin_amdgcn_mfma_f32_16x16x32_bf16(k1, xf[m], aK[1][m], 0, 0, 0);
        aV[m][0] = __builtin_amdgcn_mfma_f32_16x16x32_bf16(xf[m], v0, aV[m][0], 0, 0, 0);
        aV[m][1] = __builtin_amdgcn_mfma_f32_16x16x32_bf16(xf[m], v1, aV[m][1], 0, 0, 0);
      }
    }

    // Q pack (+bias) -> registers (bpermute source). aQ[n][m][r] = Q^T[c][tok].
    uint2 aQb[2][4];
    {
      const float* bQ = b_qkv + h * 32;
      #pragma unroll
      for (int n = 0; n < 2; ++n) {
        float4 bb = *(const float4*)(bQ + (n << 4) + (l4 << 2));
        #pragma unroll
        for (int m = 0; m < 4; ++m) {
          aQb[n][m].x = pk2(aQ[n][m][0] + bb.x, aQ[n][m][1] + bb.y);
          aQb[n][m].y = pk2(aQ[n][m][2] + bb.z, aQ[n][m][3] + bb.w);
        }
      }
    }
    // V pack (+bias) -> registers (permfrag source; r17-verified).
    uint2 aVb[4][2];
    {
      const float* bV = b_qkv + 512 + h * 32;
      #pragma unroll
      for (int m = 0; m < 4; ++m)
        #pragma unroll
        for (int n = 0; n < 2; ++n) {
          float bv = bV[(n << 4) + l15];
          aVb[m][n].x = pk2(aV[m][n][0] + bv, aV[m][n][1] + bv);
          aVb[m][n].y = pk2(aV[m][n][2] + bv, aV[m][n][3] + bv);
        }
    }
    // K epilogue (swapped: D[c][tok]) -> ks [tok][32c] stride 80 B.
    {
      const float* bK = b_qkv + 256 + h * 32;
      #pragma unroll
      for (int n = 0; n < 2; ++n) {
        int c0 = (n << 4) + (l4 << 2);
        float4 bb = *(const float4*)(bK + c0);
        #pragma unroll
        for (int m = 0; m < 4; ++m) {
          int tok = (m << 4) + l15;
          f32x4 a = aK[n][m];
          ushort4 u4;
          u4.x = f2b(a[0] + bb.x); u4.y = f2b(a[1] + bb.y);
          u4.z = f2b(a[2] + bb.z); u4.w = f2b(a[3] + bb.w);
          *(ushort4*)(ksB + tok * 80 + (c0 << 1)) = u4;
        }
      }
    }

    // ---- attention ----
    bf16x8 kf[4];
    #pragma unroll
    for (int j = 0; j < 4; ++j)
      kf[j] = *(const bf16x8*)(ksB + ((j << 4) + l15) * 80 + (l4 << 4));

    bf16x8 qf[4];
    #pragma unroll
    for (int ni = 0; ni < 4; ++ni)
      qf[ni] = permfrag(aQb[0][ni], aQb[1][ni], bpA, bpB, nsel);

    // S^T[j][i] = mfma(K, Q): reg r -> j = mj*16 + l4*4 + r; col i = ni*16 + l15.
    f32x4 st[4][4] = {};
    #pragma unroll
    for (int mj = 0; mj < 4; ++mj)
      #pragma unroll
      for (int ni = 0; ni < 4; ++ni)
        st[mj][ni] = __builtin_amdgcn_mfma_f32_16x16x32_bf16(kf[mj], qf[ni], st[mj][ni], 0, 0, 0);

    // scale + bias
    #pragma unroll
    for (int ni = 0; ni < 4; ++ni) {
      int i = (ni << 4) + l15;
      #pragma unroll
      for (int mj = 0; mj < 4; ++mj) {
        float4 bb = *(const float4*)(bias + i * 64 + (mj << 4) + (l4 << 2));
        st[mj][ni][0] = fmaf(st[mj][ni][0], SCALE_F, bb.x);
        st[mj][ni][1] = fmaf(st[mj][ni][1], SCALE_F, bb.y);
        st[mj][ni][2] = fmaf(st[mj][ni][2], SCALE_F, bb.z);
        st[mj][ni][3] = fmaf(st[mj][ni][3], SCALE_F, bb.w);
      }
    }

    // kf/qf are in registers; retire outstanding LDS reads before ps
    // overwrites ks (rule #18 guard).
    asm volatile("s_waitcnt lgkmcnt(0)" ::: "memory");
    __builtin_amdgcn_sched_barrier(0);

    // softmax over j per owned q-row; unnormalized P -> swizzled psB.
    // Row sums kept in registers; redistributed via __shfl in the epilogue.
    float invs[4];
    #pragma unroll
    for (int ni = 0; ni < 4; ++ni) {
      float mx = st[0][ni][0];
      #pragma unroll
      for (int mj = 0; mj < 4; ++mj)
        #pragma unroll
        for (int r = 0; r < 4; ++r)
          mx = fmaxf(mx, st[mj][ni][r]);
      mx = fmaxf(mx, __shfl_xor(mx, 16));
      mx = fmaxf(mx, __shfl_xor(mx, 32));
      float sum = 0.f;
      #pragma unroll
      for (int mj = 0; mj < 4; ++mj)
        #pragma unroll
        for (int r = 0; r < 4; ++r) {
          float p = __expf(st[mj][ni][r] - mx);
          st[mj][ni][r] = p;
          sum += p;
        }
      sum += __shfl_xor(sum, 16);
      sum += __shfl_xor(sum, 32);
      invs[ni] = 1.0f / sum;
      int i2 = (ni << 4) + l15;
      const int swz = (i2 & 7) << 4;
      #pragma unroll
      for (int mj = 0; mj < 4; ++mj) {
        uint2 val;
        val.x = pk2(st[mj][ni][0], st[mj][ni][1]);
        val.y = pk2(st[mj][ni][2], st[mj][ni][3]);
        *(uint2*)(psB + i2 * 128 + (((mj << 5) + (l4 << 3)) ^ swz)) = val;
      }
    }

    // V fragments via permfrag (r17-verified mapping).
    bf16x8 vf[2][2];
    #pragma unroll
    for (int nj = 0; nj < 2; ++nj)
      #pragma unroll
      for (int ks = 0; ks < 2; ++ks)
        vf[nj][ks] = permfrag(aVb[ks * 2][nj], aVb[ks * 2 + 1][nj], bpA, bpB, nsel);

    // PV: O[i][c] = sum_j P[i][j] * Vt[c][j]
    f32x4 oacc[4][2] = {};
    #pragma unroll
    for (int mi = 0; mi < 4; ++mi) {
      int i = (mi << 4) + l15;
      int swz = (i & 7) << 4;
      bf16x8 pf0 = *(const bf16x8*)(psB + i * 128 + ((l4 << 4) ^ swz));
      bf16x8 pf1 = *(const bf16x8*)(psB + i * 128 + ((64 + (l4 << 4)) ^ swz));
      #pragma unroll
      for (int nj = 0; nj < 2; ++nj) {
        oacc[mi][nj] = __builtin_amdgcn_mfma_f32_16x16x32_bf16(pf0, vf[nj][0], oacc[mi][nj], 0, 0, 0);
        oacc[mi][nj] = __builtin_amdgcn_mfma_f32_16x16x32_bf16(pf1, vf[nj][1], oacc[mi][nj], 0, 0, 0);
      }
    }

    // epilogue: row i = mi*16 + l4*4 + r, col c = nj*16 + l15.
    // inv[row] fetched from the lane owning row&15 (any l4 -> lane (l4<<2)+r).
    #pragma unroll
    for (int mi = 0; mi < 4; ++mi) {
      #pragma unroll
      for (int r = 0; r < 4; ++r) {
        int tok = (mi << 4) + (l4 << 2) + r;
        float inv = __shfl(invs[mi], (l4 << 2) + r, 64);
        int y = ((win >> 4) << 3) | (tok >> 3);
        int xp = ((win & 15) << 3) | (tok & 7);
        size_t p = ((size_t)bl * 128 + y) * 128 + xp;
        bfu* dst = aout + p * 256 + h * 32;
        #pragma unroll
        for (int nj = 0; nj < 2; ++nj)
          dst[(nj << 4) + l15] = f2b(oacc[mi][nj][r] * inv);
      }
    }

    // ps must be fully consumed before next head's K overwrites it.
    asm volatile("s_waitcnt lgkmcnt(0)" ::: "memory");
    __builtin_amdgcn_sched_barrier(0);
  }
}

// Out-projection GEMM (round-8-verified): C[m][n] = sum_k A[m][k]*B[n][k] + bias[n].
// BK=32, double-buffered, STAGE(next) -> compute -> full barrier. f32 out.
template<int NBN>
__global__ __launch_bounds__(256)
void mfma_gemm(const bfu* __restrict__ A, const bfu* __restrict__ B,
               const float* __restrict__ bias, float* __restrict__ out)
{
  __shared__ __align__(16) char lds[32768];
  const int t = threadIdx.x;
  const int lane = t & 63;
  const int l15 = lane & 15, l4 = lane >> 4;
  const int wid = t >> 6;
  const int wr = wid >> 1, wc = wid & 1;

  const int L = blockIdx.x;
  const int chunk = (NBN * 1024) >> 3;
  const int w = (L & 7) * chunk + (L >> 3);
  const int bm = w / NBN, bn = w % NBN;

  const int goff = (lane >> 2) * 256 + (((lane & 3) ^ ((lane >> 3) & 3)) << 3);
  const bfu* Ab = A + (((size_t)(bm * 128)) << 8) + goff;
  const bfu* Bb = B + (((size_t)(bn * 128)) << 8) + goff;

  f32x4 acc[4][4] = {};

  auto STAGE = [&](int buf, int kt) {
    char* dst = lds + (buf << 14);
    const bfu* ga = Ab + (kt << 5);
    const bfu* gb = Bb + (kt << 5);
    #pragma unroll
    for (int r = 0; r < 2; ++r) {
      int rowg = (wid << 5) + (r << 4);
      gload_lds16(ga + (size_t)rowg * 256, dst + (rowg << 6));
      gload_lds16(gb + (size_t)rowg * 256, dst + 8192 + (rowg << 6));
    }
  };

  STAGE(0, 0);
  __syncthreads();

  for (int kt = 0; kt < 8; ++kt) {
    if (kt < 7) STAGE((kt + 1) & 1, kt + 1);
    const char* bufp = lds + ((kt & 1) << 14);

    bf16x8 af[4], bfr[4];
    #pragma unroll
    for (int ms = 0; ms < 4; ++ms) {
      int row = (wr << 6) + (ms << 4) + l15;
      int u = (l4 ^ ((row >> 1) & 3)) << 4;
      af[ms] = *(const bf16x8*)(bufp + (row << 6) + u);
    }
    #pragma unroll
    for (int ns = 0; ns < 4; ++ns) {
      int row = (wc << 6) + (ns << 4) + l15;
      int u = (l4 ^ ((row >> 1) & 3)) << 4;
      bfr[ns] = *(const bf16x8*)(bufp + 8192 + (row << 6) + u);
    }
    #pragma unroll
    for (int ms = 0; ms < 4; ++ms)
      #pragma unroll
      for (int ns = 0; ns < 4; ++ns)
        acc[ms][ns] = __builtin_amdgcn_mfma_f32_16x16x32_bf16(af[ms], bfr[ns], acc[ms][ns], 0, 0, 0);
    if (kt < 7) __syncthreads();
  }

  #pragma unroll
  for (int ns = 0; ns < 4; ++ns) {
    int n = bn * 128 + (wc << 6) + (ns << 4) + l15;
    float bb = bias[n];
    #pragma unroll
    for (int ms = 0; ms < 4; ++ms) {
      int m = bm * 128 + (wr << 6) + (ms << 4) + (l4 << 2);
      #pragma unroll
      for (int r = 0; r < 4; ++r)
        out[((size_t)(m + r) << 8) + n] = acc[ms][ns][r] + bb;
    }
  }
}

extern "C" void kernel_launch(void* const* d_in, const int* in_sizes, int n_in,
                              void* d_out, int out_size, void* d_ws, size_t ws_size,
                              hipStream_t stream)
{
  const float* x     = (const float*)d_in[0];
  const float* w_qkv = (const float*)d_in[1];
  const float* b_qkv = (const float*)d_in[2];
  const float* w_out = (const float*)d_in[3];
  const float* b_out = (const float*)d_in[4];
  const float* pe    = (const float*)d_in[5];
  const int*   rel   = (const int*)d_in[6];
  float* out = (float*)d_out;

  char* ws = (char*)d_ws;
  bfu*   attn_ws = (bfu*)(ws);                 // [131072][256] bf16 = 64 MiB
  float* bias_ws = (float*)(ws + 67108864);    // 4096 f32
  bfu*   wqB     = (bfu*)(ws + 67125248);      // 196608 bf16 [768][256]
  bfu*   woB     = (bfu*)(ws + 67518464);      // 65536 bf16 [256][256]

  prep_kernel<<<768, 256, 0, stream>>>(w_qkv, w_out, pe, rel, wqB, woB, bias_ws);
  qkv_attn<<<2048, 256, 0, stream>>>(x, wqB, b_qkv, bias_ws, attn_ws);
  mfma_gemm<2><<<2048, 256, 0, stream>>>(attn_ws, woB, b_out, out);
}